// Round 9
// baseline (167.259 us; speedup 1.0000x reference)
//
#include <hip/hip_runtime.h>
#include <math.h>

#define NSEQ   2048
#define DMODEL 1024
#define NHEADS 16
#define HD     64

typedef short bf16x8 __attribute__((ext_vector_type(8)));
typedef float f32x4  __attribute__((ext_vector_type(4)));
typedef unsigned short ushort8_t __attribute__((ext_vector_type(8)));

// RTNE float -> bf16 bits
__device__ __forceinline__ unsigned short f2bf(float x) {
    unsigned int u = __builtin_bit_cast(unsigned int, x);
    unsigned int r = (u + 0x7FFFu + ((u >> 16) & 1u)) >> 16;
    return (unsigned short)r;
}
// v_cvt_pk_bf16_f32: D[15:0]=bf16(lo), D[31:16]=bf16(hi) (RTNE)
__device__ __forceinline__ unsigned int cvt_pk_bf16(float lo, float hi) {
    unsigned int d;
    asm("v_cvt_pk_bf16_f32 %0, %1, %2" : "=v"(d) : "v"(lo), "v"(hi));
    return d;
}

// ---------------------------------------------------------------------------
// QKV GEMM: A = x (f32, converted to bf16 during staging), B = Wq/Wk/Wv (f32,
// converted during staging; selected by bn). C[m,n] = sum_k A[m,k]*B[n,k].
// BM=BN=128, BK=64; 4 waves (2x2), wave tile 64x64.
// LDS: linear 64-u16 rows + XOR colseg swizzle (seg' = seg ^ (row&7)) -- the
// measured-conflict-free family from attn v3 (R7: 1.47e7 -> 0).
// Epilogue (R7-verified): Q/K cols -> bf16 out + per-(head,row) norms
// (qn, cq2=2/(1-qn) | kn, ck=1/(1-kn)); V cols -> bf16 out.
// ---------------------------------------------------------------------------
__global__ __launch_bounds__(256) void gemm_qkv(
    const float* __restrict__ X,
    const float* __restrict__ Wq, const float* __restrict__ Wk,
    const float* __restrict__ Wv,
    unsigned short* __restrict__ QbO, float* __restrict__ qnO,
    float* __restrict__ cq2O,
    unsigned short* __restrict__ KbO, float* __restrict__ knO,
    float* __restrict__ ckO,
    unsigned short* __restrict__ VbO)
{
    __shared__ unsigned short Ahs[128 * 64];
    __shared__ unsigned short Bhs[128 * 64];

    const int bm   = blockIdx.x * 128;
    const int bn   = blockIdx.y * 128;
    const int t    = threadIdx.x;
    const int wid  = t >> 6;
    const int lane = t & 63;
    const int g    = lane >> 4;
    const int r    = lane & 15;
    const int wm   = (wid >> 1) * 64;
    const int wn   = (wid & 1) * 64;

    const int sel = bn >> 10;
    const int bnl = bn & 1023;
    const float* Bp = (sel == 0) ? Wq : ((sel == 1) ? Wk : Wv);

    f32x4 acc[4][4];
#pragma unroll
    for (int i = 0; i < 4; ++i)
#pragma unroll
        for (int j = 0; j < 4; ++j) acc[i][j] = (f32x4){0.f, 0.f, 0.f, 0.f};

    const int srow = t >> 1;         // 0..127
    const int shal = (t & 1) * 32;   // k-col half: 0 / 32

    for (int k0 = 0; k0 < DMODEL; k0 += 64) {
        __syncthreads();
        const float* ag = &X[(size_t)(bm + srow) * DMODEL + k0 + shal];
        const float* bg = &Bp[(size_t)(bnl + srow) * DMODEL + k0 + shal];
        unsigned int apk[16], bpk[16];
#pragma unroll
        for (int c4 = 0; c4 < 8; ++c4) {
            const float4 va = *reinterpret_cast<const float4*>(ag + c4 * 4);
            apk[2 * c4]     = cvt_pk_bf16(va.x, va.y);
            apk[2 * c4 + 1] = cvt_pk_bf16(va.z, va.w);
            const float4 vb = *reinterpret_cast<const float4*>(bg + c4 * 4);
            bpk[2 * c4]     = cvt_pk_bf16(vb.x, vb.y);
            bpk[2 * c4 + 1] = cvt_pk_bf16(vb.z, vb.w);
        }
#pragma unroll
        for (int c = 0; c < 4; ++c) {
            const int seg = (t & 1) * 4 + c;
            const int sw  = (seg ^ (srow & 7)) * 8;
            uint4 wa, wb;
            wa.x = apk[4 * c]; wa.y = apk[4 * c + 1];
            wa.z = apk[4 * c + 2]; wa.w = apk[4 * c + 3];
            wb.x = bpk[4 * c]; wb.y = bpk[4 * c + 1];
            wb.z = bpk[4 * c + 2]; wb.w = bpk[4 * c + 3];
            *reinterpret_cast<uint4*>(&Ahs[srow * 64 + sw]) = wa;
            *reinterpret_cast<uint4*>(&Bhs[srow * 64 + sw]) = wb;
        }
        __syncthreads();

#pragma unroll
        for (int dc = 0; dc < 2; ++dc) {
            bf16x8 af[4], bfr[4];
#pragma unroll
            for (int mt = 0; mt < 4; ++mt)
                af[mt] = *reinterpret_cast<const bf16x8*>(
                    &Ahs[(wm + mt * 16 + r) * 64 + ((dc * 4 + g) ^ (r & 7)) * 8]);
#pragma unroll
            for (int nt = 0; nt < 4; ++nt)
                bfr[nt] = *reinterpret_cast<const bf16x8*>(
                    &Bhs[(wn + nt * 16 + r) * 64 + ((dc * 4 + g) ^ (r & 7)) * 8]);
#pragma unroll
            for (int mt = 0; mt < 4; ++mt)
#pragma unroll
                for (int nt = 0; nt < 4; ++nt)
                    acc[mt][nt] = __builtin_amdgcn_mfma_f32_16x16x32_bf16(
                        af[mt], bfr[nt], acc[mt][nt], 0, 0, 0);
        }
    }

    if (sel < 2) {
        unsigned short* Hb = sel ? KbO : QbO;
        float* narr = sel ? knO : qnO;
        float* carr = sel ? ckO : cq2O;
        const int hh = (bnl + wn) >> 6;   // one head per wave (64 cols)
#pragma unroll
        for (int mt = 0; mt < 4; ++mt) {
#pragma unroll
            for (int rg = 0; rg < 4; ++rg) {
                float ss = 0.f;
#pragma unroll
                for (int nt = 0; nt < 4; ++nt) {
                    const float v = acc[mt][nt][rg];
                    ss = fmaf(v, v, ss);
                    Hb[(size_t)(bm + wm + mt * 16 + g * 4 + rg) * 1024 +
                       bnl + wn + nt * 16 + r] = f2bf(v);
                }
                ss += __shfl_xor(ss, 1, 64);
                ss += __shfl_xor(ss, 2, 64);
                ss += __shfl_xor(ss, 4, 64);
                ss += __shfl_xor(ss, 8, 64);
                if (r == 0) {
                    const int row = bm + wm + mt * 16 + g * 4 + rg;
                    narr[hh * NSEQ + row] = ss;
                    carr[hh * NSEQ + row] = (sel ? 1.0f : 2.0f) / (1.0f - ss);
                }
            }
        }
    } else {
#pragma unroll
        for (int mt = 0; mt < 4; ++mt)
#pragma unroll
            for (int nt = 0; nt < 4; ++nt)
#pragma unroll
                for (int rg = 0; rg < 4; ++rg)
                    VbO[(size_t)(bm + wm + mt * 16 + g * 4 + rg) * 1024 +
                        bnl + wn + nt * 16 + r] = f2bf(acc[mt][nt][rg]);
    }
}

// ---------------------------------------------------------------------------
// Per-head V transpose (bf16->bf16): Vt[(h*64+d)*2048 + n] = Vb[n*1024+h*64+d]
// ---------------------------------------------------------------------------
__global__ __launch_bounds__(256) void vt_kernel_bf16(
    const unsigned short* __restrict__ Vb, unsigned short* __restrict__ Vt)
{
    __shared__ unsigned short Vs[64 * 72];
    const int h   = blockIdx.y;
    const int n0  = blockIdx.x * 64;
    const int t   = threadIdx.x;
    const int row = t >> 2;
    const int seg = (t & 3) * 16;

    const unsigned short* src = Vb + (size_t)(n0 + row) * 1024 + h * HD + seg;
    *reinterpret_cast<ushort8_t*>(&Vs[row * 72 + seg]) =
        *reinterpret_cast<const ushort8_t*>(src);
    *reinterpret_cast<ushort8_t*>(&Vs[row * 72 + seg + 8]) =
        *reinterpret_cast<const ushort8_t*>(src + 8);
    __syncthreads();

    ushort8_t a, b;
#pragma unroll
    for (int c = 0; c < 8; ++c) a[c] = Vs[(seg + c) * 72 + row];
#pragma unroll
    for (int c = 0; c < 8; ++c) b[c] = Vs[(seg + 8 + c) * 72 + row];
    unsigned short* dst = Vt + (size_t)(h * HD + row) * NSEQ + n0 + seg;
    *reinterpret_cast<ushort8_t*>(dst)     = a;
    *reinterpret_cast<ushort8_t*>(dst + 8) = b;
}

// ---------------------------------------------------------------------------
// MFMA hyperbolic attention v3 (R7-verified: 52us, 0 bank conflicts).
// Grid (NSEQ/64, NHEADS, 2). 4 waves; wave w: q rows [n0+16w,+16).
// Single-pass bf16 QK; linear 64-u16 LDS rows + XOR colseg swizzle on K/V/P.
// Weights: w = ca - sqrt(ca^2-1) = exp(-acosh(ca)); clamp ca>=1 only.
// ---------------------------------------------------------------------------
__global__ __launch_bounds__(256) void hyp_attn_v3(
    const unsigned short* __restrict__ Qb, const unsigned short* __restrict__ Kb,
    const unsigned short* __restrict__ Vt,
    const float* __restrict__ qn_a, const float* __restrict__ cq2_a,
    const float* __restrict__ kn_a, const float* __restrict__ ck_a,
    float* __restrict__ Opart, float* __restrict__ lpart)
{
    __shared__ unsigned short Khs[64 * 64];   // [j][k-seg swz]
    __shared__ unsigned short Vts[64 * 64];   // [d][j-seg swz]
    __shared__ unsigned short Ps[4][16 * 64]; // per-wave [q][j-seg swz]

    const int h    = blockIdx.y;
    const int n0   = blockIdx.x * 64;
    const int jh   = blockIdx.z;
    const int t    = threadIdx.x;
    const int wid  = t >> 6;
    const int lane = t & 63;
    const int g    = lane >> 4;
    const int r    = lane & 15;
    const int qb   = n0 + wid * 16;

    // Q A-frags: Q[qb+r][k = dc*32 + g*8 + e]
    bf16x8 qf[2];
#pragma unroll
    for (int dc = 0; dc < 2; ++dc)
        qf[dc] = *reinterpret_cast<const bf16x8*>(
            Qb + (size_t)(qb + r) * DMODEL + h * HD + dc * 32 + g * 8);

    // per-q constants for the 4 D-rows this thread owns (q = qb + g*4 + rg)
    float qn_r[4], c2q[4];
#pragma unroll
    for (int rg = 0; rg < 4; ++rg) {
        qn_r[rg] = qn_a[h * NSEQ + qb + g * 4 + rg];
        c2q[rg]  = cq2_a[h * NSEQ + qb + g * 4 + rg];
    }

    f32x4 oacc[4];
#pragma unroll
    for (int nt = 0; nt < 4; ++nt) oacc[nt] = (f32x4){0.f, 0.f, 0.f, 0.f};
    float l_acc[4] = {0.f, 0.f, 0.f, 0.f};

    const int srow = t >> 2;           // 0..63 (LDS row this thread fills)
    const int c0   = (t & 3) * 2;      // first of two 8-u16 col segments
    const int sw0  = (c0 ^ (srow & 7)) * 8;
    const int sw1  = ((c0 + 1) ^ (srow & 7)) * 8;
    const int sg   = (t & 3) * 16;     // global col offset (u16)
    unsigned short* Pw = &Ps[wid][0];

    for (int tb = 0; tb < 16; ++tb) {
        const int j0 = jh * 1024 + tb * 64;
        __syncthreads();
        // ---- stage K and V^T tiles (vector loads, swizzled LDS writes) ----
        {
            const unsigned short* ks = Kb + (size_t)(j0 + srow) * DMODEL + h * HD + sg;
            const unsigned short* vs = Vt + (size_t)(h * HD + srow) * NSEQ + j0 + sg;
            *reinterpret_cast<ushort8_t*>(&Khs[srow * 64 + sw0]) =
                *reinterpret_cast<const ushort8_t*>(ks);
            *reinterpret_cast<ushort8_t*>(&Khs[srow * 64 + sw1]) =
                *reinterpret_cast<const ushort8_t*>(ks + 8);
            *reinterpret_cast<ushort8_t*>(&Vts[srow * 64 + sw0]) =
                *reinterpret_cast<const ushort8_t*>(vs);
            *reinterpret_cast<ushort8_t*>(&Vts[srow * 64 + sw1]) =
                *reinterpret_cast<const ushort8_t*>(vs + 8);
        }
        __syncthreads();

        // ---- S tiles + distance -> w -> P (swizzled wave-private LDS) ----
#pragma unroll
        for (int jt = 0; jt < 4; ++jt) {
            f32x4 sac = (f32x4){0.f, 0.f, 0.f, 0.f};
#pragma unroll
            for (int dc = 0; dc < 2; ++dc) {
                const bf16x8 kb = *reinterpret_cast<const bf16x8*>(
                    &Khs[(jt * 16 + r) * 64 + ((dc * 4 + g) ^ (r & 7)) * 8]);
                sac = __builtin_amdgcn_mfma_f32_16x16x32_bf16(qf[dc], kb, sac, 0, 0, 0);
            }
            const int jj = j0 + jt * 16 + r;
            const float kn_v = kn_a[h * NSEQ + jj];
            const float ck_v = ck_a[h * NSEQ + jj];
#pragma unroll
            for (int rg = 0; rg < 4; ++rg) {
                const float dsq = fmaf(-2.f, sac[rg], qn_r[rg] + kn_v);
                const float ca  = fmaxf(fmaf(dsq, c2q[rg] * ck_v, 1.f), 1.0f);
                const float s2  = fmaf(ca, ca, -1.f);
                const float wj  = ca - __builtin_amdgcn_sqrtf(s2);
                l_acc[rg] += wj;
                const int qrow = g * 4 + rg;
                Pw[qrow * 64 +
                   ((2 * jt + (r >> 3)) ^ (qrow & 7)) * 8 + (r & 7)] = f2bf(wj);
            }
        }
        // Pw is wave-private: within-wave ds ordering suffices

        // ---- PV: O[q][d] += P . V ----
#pragma unroll
        for (int kc = 0; kc < 2; ++kc) {
            const bf16x8 pa = *reinterpret_cast<const bf16x8*>(
                &Pw[r * 64 + ((kc * 4 + g) ^ (r & 7)) * 8]);   // A: m=r(q), k=j
#pragma unroll
            for (int nt = 0; nt < 4; ++nt) {
                const bf16x8 vb = *reinterpret_cast<const bf16x8*>(
                    &Vts[(nt * 16 + r) * 64 + ((kc * 4 + g) ^ (r & 7)) * 8]);
                oacc[nt] = __builtin_amdgcn_mfma_f32_16x16x32_bf16(pa, vb, oacc[nt], 0, 0, 0);
            }
        }
    }

    // ---- l reduce over the 16 r-lanes ----
#pragma unroll
    for (int rg = 0; rg < 4; ++rg) {
        l_acc[rg] += __shfl_xor(l_acc[rg], 1, 64);
        l_acc[rg] += __shfl_xor(l_acc[rg], 2, 64);
        l_acc[rg] += __shfl_xor(l_acc[rg], 4, 64);
        l_acc[rg] += __shfl_xor(l_acc[rg], 8, 64);
    }

    // ---- write partials ----
    float* Op = Opart + (size_t)jh * NSEQ * DMODEL;
#pragma unroll
    for (int nt = 0; nt < 4; ++nt)
#pragma unroll
        for (int rg = 0; rg < 4; ++rg)
            Op[(size_t)(qb + g * 4 + rg) * DMODEL + h * HD + nt * 16 + r] =
                oacc[nt][rg];
    if (r == 0) {
#pragma unroll
        for (int rg = 0; rg < 4; ++rg)
            lpart[(jh * NHEADS + h) * NSEQ + qb + g * 4 + rg] = l_acc[rg];
    }
}

// ---------------------------------------------------------------------------
// Merge j-split partials: Ob = bf16((O0+O1) / (l0+l1)).
// ---------------------------------------------------------------------------
__global__ __launch_bounds__(256) void merge_kernel(
    const float* __restrict__ Opart, const float* __restrict__ lpart,
    unsigned short* __restrict__ Ob)
{
    const size_t i8 = ((size_t)blockIdx.x * 256 + threadIdx.x) * 8;
    if (i8 >= (size_t)NSEQ * DMODEL) return;
    const int n  = (int)(i8 >> 10);
    const int dm = (int)(i8 & 1023);
    const int h  = dm >> 6;
    const float li = 1.0f / (lpart[h * NSEQ + n] +
                             lpart[(NHEADS + h) * NSEQ + n]);
    const float* O0 = Opart + i8;
    const float* O1 = Opart + (size_t)NSEQ * DMODEL + i8;
    ushort8_t o;
#pragma unroll
    for (int c = 0; c < 2; ++c) {
        const float4 a = *reinterpret_cast<const float4*>(O0 + c * 4);
        const float4 b = *reinterpret_cast<const float4*>(O1 + c * 4);
        o[c * 4 + 0] = f2bf((a.x + b.x) * li);
        o[c * 4 + 1] = f2bf((a.y + b.y) * li);
        o[c * 4 + 2] = f2bf((a.z + b.z) * li);
        o[c * 4 + 3] = f2bf((a.w + b.w) * li);
    }
    *reinterpret_cast<ushort8_t*>(Ob + i8) = o;
}

// ---------------------------------------------------------------------------
// Output projection: A = Ob (bf16), B = Wo (f32, converted during staging).
// Same swizzled-LDS GEMM core. C = out (f32).
// ---------------------------------------------------------------------------
__global__ __launch_bounds__(256) void gemm_out(
    const unsigned short* __restrict__ A, const float* __restrict__ B,
    float* __restrict__ C)
{
    __shared__ unsigned short Ahs[128 * 64];
    __shared__ unsigned short Bhs[128 * 64];

    const int bm   = blockIdx.x * 128;
    const int bn   = blockIdx.y * 128;
    const int t    = threadIdx.x;
    const int wid  = t >> 6;
    const int lane = t & 63;
    const int g    = lane >> 4;
    const int r    = lane & 15;
    const int wm   = (wid >> 1) * 64;
    const int wn   = (wid & 1) * 64;

    f32x4 acc[4][4];
#pragma unroll
    for (int i = 0; i < 4; ++i)
#pragma unroll
        for (int j = 0; j < 4; ++j) acc[i][j] = (f32x4){0.f, 0.f, 0.f, 0.f};

    const int srow = t >> 1;
    const int shal = (t & 1) * 32;

    for (int k0 = 0; k0 < DMODEL; k0 += 64) {
        __syncthreads();
        const unsigned short* ag = &A[(size_t)(bm + srow) * DMODEL + k0 + shal];
        const float* bg = &B[(size_t)(bn + srow) * DMODEL + k0 + shal];
        ushort8_t av[4];
        unsigned int bpk[16];
#pragma unroll
        for (int c = 0; c < 4; ++c)
            av[c] = *reinterpret_cast<const ushort8_t*>(ag + c * 8);
#pragma unroll
        for (int c4 = 0; c4 < 8; ++c4) {
            const float4 vb = *reinterpret_cast<const float4*>(bg + c4 * 4);
            bpk[2 * c4]     = cvt_pk_bf16(vb.x, vb.y);
            bpk[2 * c4 + 1] = cvt_pk_bf16(vb.z, vb.w);
        }
#pragma unroll
        for (int c = 0; c < 4; ++c) {
            const int seg = (t & 1) * 4 + c;
            const int sw  = (seg ^ (srow & 7)) * 8;
            *reinterpret_cast<ushort8_t*>(&Ahs[srow * 64 + sw]) = av[c];
            uint4 wb;
            wb.x = bpk[4 * c]; wb.y = bpk[4 * c + 1];
            wb.z = bpk[4 * c + 2]; wb.w = bpk[4 * c + 3];
            *reinterpret_cast<uint4*>(&Bhs[srow * 64 + sw]) = wb;
        }
        __syncthreads();

#pragma unroll
        for (int dc = 0; dc < 2; ++dc) {
            bf16x8 af[4], bfr[4];
#pragma unroll
            for (int mt = 0; mt < 4; ++mt)
                af[mt] = *reinterpret_cast<const bf16x8*>(
                    &Ahs[(wm + mt * 16 + r) * 64 + ((dc * 4 + g) ^ (r & 7)) * 8]);
#pragma unroll
            for (int nt = 0; nt < 4; ++nt)
                bfr[nt] = *reinterpret_cast<const bf16x8*>(
                    &Bhs[(wn + nt * 16 + r) * 64 + ((dc * 4 + g) ^ (r & 7)) * 8]);
#pragma unroll
            for (int mt = 0; mt < 4; ++mt)
#pragma unroll
                for (int nt = 0; nt < 4; ++nt)
                    acc[mt][nt] = __builtin_amdgcn_mfma_f32_16x16x32_bf16(
                        af[mt], bfr[nt], acc[mt][nt], 0, 0, 0);
        }
    }

#pragma unroll
    for (int mt = 0; mt < 4; ++mt)
#pragma unroll
        for (int nt = 0; nt < 4; ++nt)
#pragma unroll
            for (int rg = 0; rg < 4; ++rg)
                C[(size_t)(bm + wm + mt * 16 + g * 4 + rg) * 1024 +
                  bn + wn + nt * 16 + r] = acc[mt][nt][rg];
}

// ---------------------------------------------------------------------------
extern "C" void kernel_launch(void* const* d_in, const int* in_sizes, int n_in,
                              void* d_out, int out_size, void* d_ws, size_t ws_size,
                              hipStream_t stream)
{
    const float* x  = (const float*)d_in[0];
    const float* Wq = (const float*)d_in[1];
    const float* Wk = (const float*)d_in[2];
    const float* Wv = (const float*)d_in[3];
    const float* Wo = (const float*)d_in[4];
    float* out = (float*)d_out;

    char* ws = (char*)d_ws;
    const size_t MB = 1048576;
    unsigned short* Qbuf = (unsigned short*)(ws);             // 4MB
    unsigned short* Kbuf = (unsigned short*)(ws + 4  * MB);   // 4MB
    unsigned short* Vb   = (unsigned short*)(ws + 8  * MB);   // 4MB
    unsigned short* Vt   = (unsigned short*)(ws + 12 * MB);   // 4MB
    unsigned short* Ob   = (unsigned short*)(ws + 16 * MB);   // 4MB
    float*          qn   = (float*)(ws + 20 * MB);            // 128KB
    float*          cq2  = qn  + NHEADS * NSEQ;
    float*          kn   = cq2 + NHEADS * NSEQ;
    float*          ck   = kn  + NHEADS * NSEQ;
    float*          Opart= (float*)(ws + 21 * MB);            // 16MB
    float*          lpart= (float*)(ws + 37 * MB);            // 256KB

    const dim3 blk(256);

    // 1. fused QKV projection (f32 in, bf16 staged) + norms in epilogue
    gemm_qkv<<<dim3(NSEQ / 128, 3072 / 128), blk, 0, stream>>>(
        x, Wq, Wk, Wv, Qbuf, qn, cq2, Kbuf, kn, ck, Vb);

    // 2. V transpose to [h*64+d][n]
    vt_kernel_bf16<<<dim3(NSEQ / 64, NHEADS), blk, 0, stream>>>(Vb, Vt);

    // 3. attention partials (j-split x2)
    hyp_attn_v3<<<dim3(NSEQ / 64, NHEADS, 2), blk, 0, stream>>>(
        Qbuf, Kbuf, Vt, qn, cq2, kn, ck, Opart, lpart);

    // 4. merge partials -> Ob (bf16)
    merge_kernel<<<(NSEQ * DMODEL / 8 + 255) / 256, blk, 0, stream>>>(
        Opart, lpart, Ob);

    // 5. output projection (Wo converted during staging)
    gemm_out<<<dim3(NSEQ / 128, DMODEL / 128), blk, 0, stream>>>(
        Ob, Wo, out);
}

// Round 10
// 113.331 us; speedup vs baseline: 1.4758x; 1.4758x over previous
//
#include <hip/hip_runtime.h>
#include <math.h>

#define NSEQ   2048
#define DMODEL 1024
#define NHEADS 16
#define HD     64

typedef short bf16x8 __attribute__((ext_vector_type(8)));
typedef float f32x4  __attribute__((ext_vector_type(4)));
typedef unsigned short ushort8_t __attribute__((ext_vector_type(8)));

// RTNE float -> bf16 bits
__device__ __forceinline__ unsigned short f2bf(float x) {
    unsigned int u = __builtin_bit_cast(unsigned int, x);
    unsigned int r = (u + 0x7FFFu + ((u >> 16) & 1u)) >> 16;
    return (unsigned short)r;
}

// ---------------------------------------------------------------------------
// Convert inputs to bf16: x(2M)->xb, Wq/Wk/Wv(3x1M)->Wb[3072][1024], Wo->Wob.
// (R7-verified; sequential streams at full HBM BW beat fused conversion — R9.)
// ---------------------------------------------------------------------------
__global__ __launch_bounds__(256) void convert_inputs(
    const float* __restrict__ x,  const float* __restrict__ Wq,
    const float* __restrict__ Wk, const float* __restrict__ Wv,
    const float* __restrict__ Wo,
    unsigned short* __restrict__ xb, unsigned short* __restrict__ Wb,
    unsigned short* __restrict__ Wob)
{
    const size_t i8 = ((size_t)blockIdx.x * 256 + threadIdx.x) * 8;
    const float* src;
    unsigned short* dst;
    if (i8 < (2ull << 20)) {
        src = x + i8;  dst = xb + i8;
    } else if (i8 < (5ull << 20)) {
        const size_t o = i8 - (2ull << 20);
        const size_t s = o >> 20;
        src = (s == 0 ? Wq : (s == 1 ? Wk : Wv)) + (o & ((1u << 20) - 1));
        dst = Wb + o;
    } else {
        const size_t o = i8 - (5ull << 20);
        src = Wo + o;  dst = Wob + o;
    }
    const float4 v0 = *reinterpret_cast<const float4*>(src);
    const float4 v1 = *reinterpret_cast<const float4*>(src + 4);
    ushort8_t r;
    r[0] = f2bf(v0.x); r[1] = f2bf(v0.y); r[2] = f2bf(v0.z); r[3] = f2bf(v0.w);
    r[4] = f2bf(v1.x); r[5] = f2bf(v1.y); r[6] = f2bf(v1.z); r[7] = f2bf(v1.w);
    *reinterpret_cast<ushort8_t*>(dst) = r;
}

// ---------------------------------------------------------------------------
// bf16 MFMA GEMM (B-transposed): C[m,n] = sum_k A[m,k]*B[n,k], fp32 acc.
// BM=BN=128, BK=64; 4 waves (2x2), wave tile 64x64.
// LDS: linear 64-u16 rows + XOR colseg swizzle (seg' = seg ^ (row&7)) — the
// measured-conflict-free family from attn v3 (R7: 1.47e7 -> 0). Reads 2-way
// (free); staging writes <=4-way.
// QKV=1: cols 0-1023 (Q) / 1024-2047 (K): bf16 out + per-(head,row) norms
//        (qn, cq2=2/(1-qn) | kn, ck=1/(1-kn)); cols 2048-3071 (V): bf16 out.
// QKV=0: plain f32 output C0 (N=1024).
// ---------------------------------------------------------------------------
template <int QKV>
__global__ __launch_bounds__(256) void gemm_bt_bf16(
    const unsigned short* __restrict__ A, const unsigned short* __restrict__ B,
    float* __restrict__ C0,
    unsigned short* __restrict__ QbO, float* __restrict__ qnO,
    float* __restrict__ cq2O,
    unsigned short* __restrict__ KbO, float* __restrict__ knO,
    float* __restrict__ ckO,
    unsigned short* __restrict__ VbO)
{
    __shared__ unsigned short Ahs[128 * 64];
    __shared__ unsigned short Bhs[128 * 64];

    const int bm   = blockIdx.x * 128;
    const int bn   = blockIdx.y * 128;
    const int t    = threadIdx.x;
    const int wid  = t >> 6;
    const int lane = t & 63;
    const int g    = lane >> 4;
    const int r    = lane & 15;
    const int wm   = (wid >> 1) * 64;
    const int wn   = (wid & 1) * 64;

    f32x4 acc[4][4];
#pragma unroll
    for (int i = 0; i < 4; ++i)
#pragma unroll
        for (int j = 0; j < 4; ++j) acc[i][j] = (f32x4){0.f, 0.f, 0.f, 0.f};

    const int srow = t >> 1;         // 0..127
    const int shal = t & 1;          // k-half selector

    for (int k0 = 0; k0 < DMODEL; k0 += 64) {
        __syncthreads();
        ushort8_t av[4], bv[4];
#pragma unroll
        for (int c = 0; c < 4; ++c) {
            av[c] = *reinterpret_cast<const ushort8_t*>(
                &A[(size_t)(bm + srow) * DMODEL + k0 + shal * 32 + c * 8]);
            bv[c] = *reinterpret_cast<const ushort8_t*>(
                &B[(size_t)(bn + srow) * DMODEL + k0 + shal * 32 + c * 8]);
        }
#pragma unroll
        for (int c = 0; c < 4; ++c) {
            const int sw = ((shal * 4 + c) ^ (srow & 7)) * 8;
            *reinterpret_cast<ushort8_t*>(&Ahs[srow * 64 + sw]) = av[c];
            *reinterpret_cast<ushort8_t*>(&Bhs[srow * 64 + sw]) = bv[c];
        }
        __syncthreads();

#pragma unroll
        for (int dc = 0; dc < 2; ++dc) {
            bf16x8 af[4], bfr[4];
#pragma unroll
            for (int mt = 0; mt < 4; ++mt)
                af[mt] = *reinterpret_cast<const bf16x8*>(
                    &Ahs[(wm + mt * 16 + r) * 64 + ((dc * 4 + g) ^ (r & 7)) * 8]);
#pragma unroll
            for (int nt = 0; nt < 4; ++nt)
                bfr[nt] = *reinterpret_cast<const bf16x8*>(
                    &Bhs[(wn + nt * 16 + r) * 64 + ((dc * 4 + g) ^ (r & 7)) * 8]);
#pragma unroll
            for (int mt = 0; mt < 4; ++mt)
#pragma unroll
                for (int nt = 0; nt < 4; ++nt)
                    acc[mt][nt] = __builtin_amdgcn_mfma_f32_16x16x32_bf16(
                        af[mt], bfr[nt], acc[mt][nt], 0, 0, 0);
        }
    }

    if (QKV) {
        const int sel = bn >> 10;
        const int bnl = bn & 1023;
        if (sel < 2) {
            unsigned short* Hb = sel ? KbO : QbO;
            float* narr = sel ? knO : qnO;
            float* carr = sel ? ckO : cq2O;
            const int hh = (bnl + wn) >> 6;   // one head per wave (64 cols)
#pragma unroll
            for (int mt = 0; mt < 4; ++mt) {
#pragma unroll
                for (int rg = 0; rg < 4; ++rg) {
                    float ss = 0.f;
#pragma unroll
                    for (int nt = 0; nt < 4; ++nt) {
                        const float v = acc[mt][nt][rg];
                        ss = fmaf(v, v, ss);
                        Hb[(size_t)(bm + wm + mt * 16 + g * 4 + rg) * 1024 +
                           bnl + wn + nt * 16 + r] = f2bf(v);
                    }
                    ss += __shfl_xor(ss, 1, 64);
                    ss += __shfl_xor(ss, 2, 64);
                    ss += __shfl_xor(ss, 4, 64);
                    ss += __shfl_xor(ss, 8, 64);
                    if (r == 0) {
                        const int row = bm + wm + mt * 16 + g * 4 + rg;
                        narr[hh * NSEQ + row] = ss;
                        carr[hh * NSEQ + row] = (sel ? 1.0f : 2.0f) / (1.0f - ss);
                    }
                }
            }
        } else {
#pragma unroll
            for (int mt = 0; mt < 4; ++mt)
#pragma unroll
                for (int nt = 0; nt < 4; ++nt)
#pragma unroll
                    for (int rg = 0; rg < 4; ++rg)
                        VbO[(size_t)(bm + wm + mt * 16 + g * 4 + rg) * 1024 +
                            bnl + wn + nt * 16 + r] = f2bf(acc[mt][nt][rg]);
        }
    } else {
#pragma unroll
        for (int mt = 0; mt < 4; ++mt)
#pragma unroll
            for (int nt = 0; nt < 4; ++nt)
#pragma unroll
                for (int rg = 0; rg < 4; ++rg)
                    C0[(size_t)(bm + wm + mt * 16 + g * 4 + rg) * 1024 +
                       bn + wn + nt * 16 + r] = acc[mt][nt][rg];
    }
}

// ---------------------------------------------------------------------------
// Per-head V transpose (bf16->bf16): Vt[(h*64+d)*2048 + n] = Vb[n*1024+h*64+d]
// ---------------------------------------------------------------------------
__global__ __launch_bounds__(256) void vt_kernel_bf16(
    const unsigned short* __restrict__ Vb, unsigned short* __restrict__ Vt)
{
    __shared__ unsigned short Vs[64 * 72];
    const int h   = blockIdx.y;
    const int n0  = blockIdx.x * 64;
    const int t   = threadIdx.x;
    const int row = t >> 2;
    const int seg = (t & 3) * 16;

    const unsigned short* src = Vb + (size_t)(n0 + row) * 1024 + h * HD + seg;
    *reinterpret_cast<ushort8_t*>(&Vs[row * 72 + seg]) =
        *reinterpret_cast<const ushort8_t*>(src);
    *reinterpret_cast<ushort8_t*>(&Vs[row * 72 + seg + 8]) =
        *reinterpret_cast<const ushort8_t*>(src + 8);
    __syncthreads();

    ushort8_t a, b;
#pragma unroll
    for (int c = 0; c < 8; ++c) a[c] = Vs[(seg + c) * 72 + row];
#pragma unroll
    for (int c = 0; c < 8; ++c) b[c] = Vs[(seg + 8 + c) * 72 + row];
    unsigned short* dst = Vt + (size_t)(h * HD + row) * NSEQ + n0 + seg;
    *reinterpret_cast<ushort8_t*>(dst)     = a;
    *reinterpret_cast<ushort8_t*>(dst + 8) = b;
}

// ---------------------------------------------------------------------------
// MFMA hyperbolic attention v3 (R7-verified: 52us, 0 bank conflicts).
// Grid (NSEQ/64, NHEADS, 2). 4 waves; wave w: q rows [n0+16w,+16).
// Single-pass bf16 QK; linear 64-u16 LDS rows + XOR colseg swizzle on K/V/P.
// Weights: w = ca - sqrt(ca^2-1) = exp(-acosh(ca)); clamp ca>=1 only.
// ---------------------------------------------------------------------------
__global__ __launch_bounds__(256) void hyp_attn_v3(
    const unsigned short* __restrict__ Qb, const unsigned short* __restrict__ Kb,
    const unsigned short* __restrict__ Vt,
    const float* __restrict__ qn_a, const float* __restrict__ cq2_a,
    const float* __restrict__ kn_a, const float* __restrict__ ck_a,
    float* __restrict__ Opart, float* __restrict__ lpart)
{
    __shared__ unsigned short Khs[64 * 64];   // [j][k-seg swz]
    __shared__ unsigned short Vts[64 * 64];   // [d][j-seg swz]
    __shared__ unsigned short Ps[4][16 * 64]; // per-wave [q][j-seg swz]

    const int h    = blockIdx.y;
    const int n0   = blockIdx.x * 64;
    const int jh   = blockIdx.z;
    const int t    = threadIdx.x;
    const int wid  = t >> 6;
    const int lane = t & 63;
    const int g    = lane >> 4;
    const int r    = lane & 15;
    const int qb   = n0 + wid * 16;

    // Q A-frags: Q[qb+r][k = dc*32 + g*8 + e]
    bf16x8 qf[2];
#pragma unroll
    for (int dc = 0; dc < 2; ++dc)
        qf[dc] = *reinterpret_cast<const bf16x8*>(
            Qb + (size_t)(qb + r) * DMODEL + h * HD + dc * 32 + g * 8);

    // per-q constants for the 4 D-rows this thread owns (q = qb + g*4 + rg)
    float qn_r[4], c2q[4];
#pragma unroll
    for (int rg = 0; rg < 4; ++rg) {
        qn_r[rg] = qn_a[h * NSEQ + qb + g * 4 + rg];
        c2q[rg]  = cq2_a[h * NSEQ + qb + g * 4 + rg];
    }

    f32x4 oacc[4];
#pragma unroll
    for (int nt = 0; nt < 4; ++nt) oacc[nt] = (f32x4){0.f, 0.f, 0.f, 0.f};
    float l_acc[4] = {0.f, 0.f, 0.f, 0.f};

    const int srow = t >> 2;           // 0..63 (LDS row this thread fills)
    const int c0   = (t & 3) * 2;      // first of two 8-u16 col segments
    const int sw0  = (c0 ^ (srow & 7)) * 8;
    const int sw1  = ((c0 + 1) ^ (srow & 7)) * 8;
    const int sg   = (t & 3) * 16;     // global col offset (u16)
    unsigned short* Pw = &Ps[wid][0];

    for (int tb = 0; tb < 16; ++tb) {
        const int j0 = jh * 1024 + tb * 64;
        __syncthreads();
        // ---- stage K and V^T tiles (vector loads, swizzled LDS writes) ----
        {
            const unsigned short* ks = Kb + (size_t)(j0 + srow) * DMODEL + h * HD + sg;
            const unsigned short* vs = Vt + (size_t)(h * HD + srow) * NSEQ + j0 + sg;
            *reinterpret_cast<ushort8_t*>(&Khs[srow * 64 + sw0]) =
                *reinterpret_cast<const ushort8_t*>(ks);
            *reinterpret_cast<ushort8_t*>(&Khs[srow * 64 + sw1]) =
                *reinterpret_cast<const ushort8_t*>(ks + 8);
            *reinterpret_cast<ushort8_t*>(&Vts[srow * 64 + sw0]) =
                *reinterpret_cast<const ushort8_t*>(vs);
            *reinterpret_cast<ushort8_t*>(&Vts[srow * 64 + sw1]) =
                *reinterpret_cast<const ushort8_t*>(vs + 8);
        }
        __syncthreads();

        // ---- S tiles + distance -> w -> P (swizzled wave-private LDS) ----
#pragma unroll
        for (int jt = 0; jt < 4; ++jt) {
            f32x4 sac = (f32x4){0.f, 0.f, 0.f, 0.f};
#pragma unroll
            for (int dc = 0; dc < 2; ++dc) {
                const bf16x8 kb = *reinterpret_cast<const bf16x8*>(
                    &Khs[(jt * 16 + r) * 64 + ((dc * 4 + g) ^ (r & 7)) * 8]);
                sac = __builtin_amdgcn_mfma_f32_16x16x32_bf16(qf[dc], kb, sac, 0, 0, 0);
            }
            const int jj = j0 + jt * 16 + r;
            const float kn_v = kn_a[h * NSEQ + jj];
            const float ck_v = ck_a[h * NSEQ + jj];
#pragma unroll
            for (int rg = 0; rg < 4; ++rg) {
                const float dsq = fmaf(-2.f, sac[rg], qn_r[rg] + kn_v);
                const float ca  = fmaxf(fmaf(dsq, c2q[rg] * ck_v, 1.f), 1.0f);
                const float s2  = fmaf(ca, ca, -1.f);
                const float wj  = ca - __builtin_amdgcn_sqrtf(s2);
                l_acc[rg] += wj;
                const int qrow = g * 4 + rg;
                Pw[qrow * 64 +
                   ((2 * jt + (r >> 3)) ^ (qrow & 7)) * 8 + (r & 7)] = f2bf(wj);
            }
        }
        // Pw is wave-private: within-wave ds ordering suffices

        // ---- PV: O[q][d] += P . V ----
#pragma unroll
        for (int kc = 0; kc < 2; ++kc) {
            const bf16x8 pa = *reinterpret_cast<const bf16x8*>(
                &Pw[r * 64 + ((kc * 4 + g) ^ (r & 7)) * 8]);   // A: m=r(q), k=j
#pragma unroll
            for (int nt = 0; nt < 4; ++nt) {
                const bf16x8 vb = *reinterpret_cast<const bf16x8*>(
                    &Vts[(nt * 16 + r) * 64 + ((kc * 4 + g) ^ (r & 7)) * 8]);
                oacc[nt] = __builtin_amdgcn_mfma_f32_16x16x32_bf16(pa, vb, oacc[nt], 0, 0, 0);
            }
        }
    }

    // ---- l reduce over the 16 r-lanes ----
#pragma unroll
    for (int rg = 0; rg < 4; ++rg) {
        l_acc[rg] += __shfl_xor(l_acc[rg], 1, 64);
        l_acc[rg] += __shfl_xor(l_acc[rg], 2, 64);
        l_acc[rg] += __shfl_xor(l_acc[rg], 4, 64);
        l_acc[rg] += __shfl_xor(l_acc[rg], 8, 64);
    }

    // ---- write partials ----
    float* Op = Opart + (size_t)jh * NSEQ * DMODEL;
#pragma unroll
    for (int nt = 0; nt < 4; ++nt)
#pragma unroll
        for (int rg = 0; rg < 4; ++rg)
            Op[(size_t)(qb + g * 4 + rg) * DMODEL + h * HD + nt * 16 + r] =
                oacc[nt][rg];
    if (r == 0) {
#pragma unroll
        for (int rg = 0; rg < 4; ++rg)
            lpart[(jh * NHEADS + h) * NSEQ + qb + g * 4 + rg] = l_acc[rg];
    }
}

// ---------------------------------------------------------------------------
// Merge j-split partials: Ob = bf16((O0+O1) / (l0+l1)).
// ---------------------------------------------------------------------------
__global__ __launch_bounds__(256) void merge_kernel(
    const float* __restrict__ Opart, const float* __restrict__ lpart,
    unsigned short* __restrict__ Ob)
{
    const size_t i8 = ((size_t)blockIdx.x * 256 + threadIdx.x) * 8;
    if (i8 >= (size_t)NSEQ * DMODEL) return;
    const int n  = (int)(i8 >> 10);
    const int dm = (int)(i8 & 1023);
    const int h  = dm >> 6;
    const float li = 1.0f / (lpart[h * NSEQ + n] +
                             lpart[(NHEADS + h) * NSEQ + n]);
    const float* O0 = Opart + i8;
    const float* O1 = Opart + (size_t)NSEQ * DMODEL + i8;
    ushort8_t o;
#pragma unroll
    for (int c = 0; c < 2; ++c) {
        const float4 a = *reinterpret_cast<const float4*>(O0 + c * 4);
        const float4 b = *reinterpret_cast<const float4*>(O1 + c * 4);
        o[c * 4 + 0] = f2bf((a.x + b.x) * li);
        o[c * 4 + 1] = f2bf((a.y + b.y) * li);
        o[c * 4 + 2] = f2bf((a.z + b.z) * li);
        o[c * 4 + 3] = f2bf((a.w + b.w) * li);
    }
    *reinterpret_cast<ushort8_t*>(Ob + i8) = o;
}

// ---------------------------------------------------------------------------
extern "C" void kernel_launch(void* const* d_in, const int* in_sizes, int n_in,
                              void* d_out, int out_size, void* d_ws, size_t ws_size,
                              hipStream_t stream)
{
    const float* x  = (const float*)d_in[0];
    const float* Wq = (const float*)d_in[1];
    const float* Wk = (const float*)d_in[2];
    const float* Wv = (const float*)d_in[3];
    const float* Wo = (const float*)d_in[4];
    float* out = (float*)d_out;

    char* ws = (char*)d_ws;
    const size_t MB = 1048576;
    unsigned short* xb   = (unsigned short*)(ws);             // 4MB (-> Ob)
    unsigned short* Wb   = (unsigned short*)(ws + 4  * MB);   // 6MB
    unsigned short* Wob  = (unsigned short*)(ws + 10 * MB);   // 2MB
    unsigned short* Qbuf = (unsigned short*)(ws + 12 * MB);   // 4MB
    unsigned short* Kbuf = (unsigned short*)(ws + 16 * MB);   // 4MB
    unsigned short* Vb   = (unsigned short*)(ws + 20 * MB);   // 4MB
    unsigned short* Vt   = (unsigned short*)(ws + 24 * MB);   // 4MB
    float*          qn   = (float*)(ws + 28 * MB);            // 128KB
    float*          cq2  = qn  + NHEADS * NSEQ;
    float*          kn   = cq2 + NHEADS * NSEQ;
    float*          ck   = kn  + NHEADS * NSEQ;
    float*          Opart= (float*)(ws + 29 * MB);            // 16MB
    float*          lpart= (float*)(ws + 45 * MB);            // 256KB
    unsigned short* Ob   = xb;   // xb dead after QKV GEMM

    const dim3 blk(256);

    // 1. fp32 -> bf16 conversions
    convert_inputs<<<3072, blk, 0, stream>>>(x, Wq, Wk, Wv, Wo, xb, Wb, Wob);

    // 2. fused QKV projection (bf16 in/out) + norms in epilogue
    gemm_bt_bf16<1><<<dim3(NSEQ / 128, 3072 / 128), blk, 0, stream>>>(
        xb, Wb, nullptr, Qbuf, qn, cq2, Kbuf, kn, ck, Vb);

    // 3. V transpose to [h*64+d][n]
    vt_kernel_bf16<<<dim3(NSEQ / 64, NHEADS), blk, 0, stream>>>(Vb, Vt);

    // 4. attention partials (j-split x2)
    hyp_attn_v3<<<dim3(NSEQ / 64, NHEADS, 2), blk, 0, stream>>>(
        Qbuf, Kbuf, Vt, qn, cq2, kn, ck, Opart, lpart);

    // 5. merge partials -> Ob (bf16)
    merge_kernel<<<(NSEQ * DMODEL / 8 + 255) / 256, blk, 0, stream>>>(
        Opart, lpart, Ob);

    // 6. output projection
    gemm_bt_bf16<0><<<dim3(NSEQ / 128, DMODEL / 128), blk, 0, stream>>>(
        Ob, Wob, out, nullptr, nullptr, nullptr,
        nullptr, nullptr, nullptr, nullptr);
}

// Round 11
// 105.733 us; speedup vs baseline: 1.5819x; 1.0719x over previous
//
#include <hip/hip_runtime.h>
#include <math.h>

#define NSEQ   2048
#define DMODEL 1024
#define NHEADS 16
#define HD     64

typedef short bf16x8 __attribute__((ext_vector_type(8)));
typedef float f32x4  __attribute__((ext_vector_type(4)));
typedef unsigned short ushort8_t __attribute__((ext_vector_type(8)));

// RTNE float -> bf16 bits
__device__ __forceinline__ unsigned short f2bf(float x) {
    unsigned int u = __builtin_bit_cast(unsigned int, x);
    unsigned int r = (u + 0x7FFFu + ((u >> 16) & 1u)) >> 16;
    return (unsigned short)r;
}

// ---------------------------------------------------------------------------
// Convert inputs to bf16: x(2M)->xb, Wq/Wk/Wv(3x1M)->Wb[3072][1024], Wo->Wob.
// ---------------------------------------------------------------------------
__global__ __launch_bounds__(256) void convert_inputs(
    const float* __restrict__ x,  const float* __restrict__ Wq,
    const float* __restrict__ Wk, const float* __restrict__ Wv,
    const float* __restrict__ Wo,
    unsigned short* __restrict__ xb, unsigned short* __restrict__ Wb,
    unsigned short* __restrict__ Wob)
{
    const size_t i8 = ((size_t)blockIdx.x * 256 + threadIdx.x) * 8;
    const float* src;
    unsigned short* dst;
    if (i8 < (2ull << 20)) {
        src = x + i8;  dst = xb + i8;
    } else if (i8 < (5ull << 20)) {
        const size_t o = i8 - (2ull << 20);
        const size_t s = o >> 20;
        src = (s == 0 ? Wq : (s == 1 ? Wk : Wv)) + (o & ((1u << 20) - 1));
        dst = Wb + o;
    } else {
        const size_t o = i8 - (5ull << 20);
        src = Wo + o;  dst = Wob + o;
    }
    const float4 v0 = *reinterpret_cast<const float4*>(src);
    const float4 v1 = *reinterpret_cast<const float4*>(src + 4);
    ushort8_t r;
    r[0] = f2bf(v0.x); r[1] = f2bf(v0.y); r[2] = f2bf(v0.z); r[3] = f2bf(v0.w);
    r[4] = f2bf(v1.x); r[5] = f2bf(v1.y); r[6] = f2bf(v1.z); r[7] = f2bf(v1.w);
    *reinterpret_cast<ushort8_t*>(dst) = r;
}

// ---------------------------------------------------------------------------
// bf16 MFMA GEMM (B-transposed), BM=128 x BN=64, BK=64; 4 waves stacked in M
// (wave tile 32x64 -> one head = 64 cols stays per-block, norm reduce intact).
// Occupancy-driven geometry: qkv grid = 768 blocks (3/CU), out = 256 (1/CU).
// LDS: linear 64-u16 rows + XOR colseg swizzle (verified family, R7).
// QKV=1: cols 0-1023 (Q) / 1024-2047 (K): bf16 out + norms; 2048-3071 (V).
// QKV=0: plain f32 output C0 (N=1024).
// ---------------------------------------------------------------------------
template <int QKV>
__global__ __launch_bounds__(256) void gemm_bt_bf16(
    const unsigned short* __restrict__ A, const unsigned short* __restrict__ B,
    float* __restrict__ C0,
    unsigned short* __restrict__ QbO, float* __restrict__ qnO,
    float* __restrict__ cq2O,
    unsigned short* __restrict__ KbO, float* __restrict__ knO,
    float* __restrict__ ckO,
    unsigned short* __restrict__ VbO)
{
    __shared__ unsigned short Ahs[128 * 64];
    __shared__ unsigned short Bhs[64 * 64];

    const int bm   = blockIdx.x * 128;
    const int bn   = blockIdx.y * 64;
    const int t    = threadIdx.x;
    const int wid  = t >> 6;
    const int lane = t & 63;
    const int g    = lane >> 4;
    const int r    = lane & 15;
    const int wm   = wid * 32;           // wave tile 32(M) x 64(N)

    const int sel = QKV ? (bn >> 10) : 0;
    const int bnl = QKV ? (bn & 1023) : bn;

    f32x4 acc[2][4];
#pragma unroll
    for (int i = 0; i < 2; ++i)
#pragma unroll
        for (int j = 0; j < 4; ++j) acc[i][j] = (f32x4){0.f, 0.f, 0.f, 0.f};

    const int srowA = t >> 1;        // 0..127
    const int shalA = t & 1;         // k-half
    const int srowB = t >> 2;        // 0..63
    const int squadB = t & 3;        // two 8-u16 chunks at seg = squadB*2 + c

    for (int k0 = 0; k0 < DMODEL; k0 += 64) {
        __syncthreads();
        ushort8_t av[4], bv[2];
#pragma unroll
        for (int c = 0; c < 4; ++c)
            av[c] = *reinterpret_cast<const ushort8_t*>(
                &A[(size_t)(bm + srowA) * DMODEL + k0 + shalA * 32 + c * 8]);
#pragma unroll
        for (int c = 0; c < 2; ++c)
            bv[c] = *reinterpret_cast<const ushort8_t*>(
                &B[(size_t)(bn + srowB) * DMODEL + k0 + (squadB * 2 + c) * 8]);
#pragma unroll
        for (int c = 0; c < 4; ++c) {
            const int sw = ((shalA * 4 + c) ^ (srowA & 7)) * 8;
            *reinterpret_cast<ushort8_t*>(&Ahs[srowA * 64 + sw]) = av[c];
        }
#pragma unroll
        for (int c = 0; c < 2; ++c) {
            const int sw = ((squadB * 2 + c) ^ (srowB & 7)) * 8;
            *reinterpret_cast<ushort8_t*>(&Bhs[srowB * 64 + sw]) = bv[c];
        }
        __syncthreads();

#pragma unroll
        for (int dc = 0; dc < 2; ++dc) {
            bf16x8 af[2], bfr[4];
#pragma unroll
            for (int mt = 0; mt < 2; ++mt)
                af[mt] = *reinterpret_cast<const bf16x8*>(
                    &Ahs[(wm + mt * 16 + r) * 64 + ((dc * 4 + g) ^ (r & 7)) * 8]);
#pragma unroll
            for (int nt = 0; nt < 4; ++nt)
                bfr[nt] = *reinterpret_cast<const bf16x8*>(
                    &Bhs[(nt * 16 + r) * 64 + ((dc * 4 + g) ^ (r & 7)) * 8]);
#pragma unroll
            for (int mt = 0; mt < 2; ++mt)
#pragma unroll
                for (int nt = 0; nt < 4; ++nt)
                    acc[mt][nt] = __builtin_amdgcn_mfma_f32_16x16x32_bf16(
                        af[mt], bfr[nt], acc[mt][nt], 0, 0, 0);
        }
    }

    if (QKV) {
        if (sel < 2) {
            unsigned short* Hb = sel ? KbO : QbO;
            float* narr = sel ? knO : qnO;
            float* carr = sel ? ckO : cq2O;
            const int hh = bnl >> 6;   // one head per block (64 cols)
#pragma unroll
            for (int mt = 0; mt < 2; ++mt) {
#pragma unroll
                for (int rg = 0; rg < 4; ++rg) {
                    float ss = 0.f;
#pragma unroll
                    for (int nt = 0; nt < 4; ++nt) {
                        const float v = acc[mt][nt][rg];
                        ss = fmaf(v, v, ss);
                        Hb[(size_t)(bm + wm + mt * 16 + g * 4 + rg) * 1024 +
                           bnl + nt * 16 + r] = f2bf(v);
                    }
                    ss += __shfl_xor(ss, 1, 64);
                    ss += __shfl_xor(ss, 2, 64);
                    ss += __shfl_xor(ss, 4, 64);
                    ss += __shfl_xor(ss, 8, 64);
                    if (r == 0) {
                        const int row = bm + wm + mt * 16 + g * 4 + rg;
                        narr[hh * NSEQ + row] = ss;
                        carr[hh * NSEQ + row] = (sel ? 1.0f : 2.0f) / (1.0f - ss);
                    }
                }
            }
        } else {
#pragma unroll
            for (int mt = 0; mt < 2; ++mt)
#pragma unroll
                for (int nt = 0; nt < 4; ++nt)
#pragma unroll
                    for (int rg = 0; rg < 4; ++rg)
                        VbO[(size_t)(bm + wm + mt * 16 + g * 4 + rg) * 1024 +
                            bnl + nt * 16 + r] = f2bf(acc[mt][nt][rg]);
        }
    } else {
#pragma unroll
        for (int mt = 0; mt < 2; ++mt)
#pragma unroll
            for (int nt = 0; nt < 4; ++nt)
#pragma unroll
                for (int rg = 0; rg < 4; ++rg)
                    C0[(size_t)(bm + wm + mt * 16 + g * 4 + rg) * 1024 +
                       bnl + nt * 16 + r] = acc[mt][nt][rg];
    }
}

// ---------------------------------------------------------------------------
// Per-head V transpose (bf16->bf16): Vt[(h*64+d)*2048 + n] = Vb[n*1024+h*64+d]
// ---------------------------------------------------------------------------
__global__ __launch_bounds__(256) void vt_kernel_bf16(
    const unsigned short* __restrict__ Vb, unsigned short* __restrict__ Vt)
{
    __shared__ unsigned short Vs[64 * 72];
    const int h   = blockIdx.y;
    const int n0  = blockIdx.x * 64;
    const int t   = threadIdx.x;
    const int row = t >> 2;
    const int seg = (t & 3) * 16;

    const unsigned short* src = Vb + (size_t)(n0 + row) * 1024 + h * HD + seg;
    *reinterpret_cast<ushort8_t*>(&Vs[row * 72 + seg]) =
        *reinterpret_cast<const ushort8_t*>(src);
    *reinterpret_cast<ushort8_t*>(&Vs[row * 72 + seg + 8]) =
        *reinterpret_cast<const ushort8_t*>(src + 8);
    __syncthreads();

    ushort8_t a, b;
#pragma unroll
    for (int c = 0; c < 8; ++c) a[c] = Vs[(seg + c) * 72 + row];
#pragma unroll
    for (int c = 0; c < 8; ++c) b[c] = Vs[(seg + 8 + c) * 72 + row];
    unsigned short* dst = Vt + (size_t)(h * HD + row) * NSEQ + n0 + seg;
    *reinterpret_cast<ushort8_t*>(dst)     = a;
    *reinterpret_cast<ushort8_t*>(dst + 8) = b;
}

// ---------------------------------------------------------------------------
// MFMA hyperbolic attention v3 (R7-verified core), j-split x njh (runtime).
// Grid (NSEQ/64, NHEADS, njh). 4 waves; wave w: q rows [n0+16w,+16).
// ---------------------------------------------------------------------------
__global__ __launch_bounds__(256) void hyp_attn_v3(
    const unsigned short* __restrict__ Qb, const unsigned short* __restrict__ Kb,
    const unsigned short* __restrict__ Vt,
    const float* __restrict__ qn_a, const float* __restrict__ cq2_a,
    const float* __restrict__ kn_a, const float* __restrict__ ck_a,
    float* __restrict__ Opart, float* __restrict__ lpart, int jspan)
{
    __shared__ unsigned short Khs[64 * 64];   // [j][k-seg swz]
    __shared__ unsigned short Vts[64 * 64];   // [d][j-seg swz]
    __shared__ unsigned short Ps[4][16 * 64]; // per-wave [q][j-seg swz]

    const int h    = blockIdx.y;
    const int n0   = blockIdx.x * 64;
    const int jh   = blockIdx.z;
    const int t    = threadIdx.x;
    const int wid  = t >> 6;
    const int lane = t & 63;
    const int g    = lane >> 4;
    const int r    = lane & 15;
    const int qb   = n0 + wid * 16;

    bf16x8 qf[2];
#pragma unroll
    for (int dc = 0; dc < 2; ++dc)
        qf[dc] = *reinterpret_cast<const bf16x8*>(
            Qb + (size_t)(qb + r) * DMODEL + h * HD + dc * 32 + g * 8);

    float qn_r[4], c2q[4];
#pragma unroll
    for (int rg = 0; rg < 4; ++rg) {
        qn_r[rg] = qn_a[h * NSEQ + qb + g * 4 + rg];
        c2q[rg]  = cq2_a[h * NSEQ + qb + g * 4 + rg];
    }

    f32x4 oacc[4];
#pragma unroll
    for (int nt = 0; nt < 4; ++nt) oacc[nt] = (f32x4){0.f, 0.f, 0.f, 0.f};
    float l_acc[4] = {0.f, 0.f, 0.f, 0.f};

    const int srow = t >> 2;
    const int c0   = (t & 3) * 2;
    const int sw0  = (c0 ^ (srow & 7)) * 8;
    const int sw1  = ((c0 + 1) ^ (srow & 7)) * 8;
    const int sg   = (t & 3) * 16;
    unsigned short* Pw = &Ps[wid][0];

    const int ntb = jspan >> 6;
    for (int tb = 0; tb < ntb; ++tb) {
        const int j0 = jh * jspan + tb * 64;
        __syncthreads();
        {
            const unsigned short* ks = Kb + (size_t)(j0 + srow) * DMODEL + h * HD + sg;
            const unsigned short* vs = Vt + (size_t)(h * HD + srow) * NSEQ + j0 + sg;
            *reinterpret_cast<ushort8_t*>(&Khs[srow * 64 + sw0]) =
                *reinterpret_cast<const ushort8_t*>(ks);
            *reinterpret_cast<ushort8_t*>(&Khs[srow * 64 + sw1]) =
                *reinterpret_cast<const ushort8_t*>(ks + 8);
            *reinterpret_cast<ushort8_t*>(&Vts[srow * 64 + sw0]) =
                *reinterpret_cast<const ushort8_t*>(vs);
            *reinterpret_cast<ushort8_t*>(&Vts[srow * 64 + sw1]) =
                *reinterpret_cast<const ushort8_t*>(vs + 8);
        }
        __syncthreads();

#pragma unroll
        for (int jt = 0; jt < 4; ++jt) {
            f32x4 sac = (f32x4){0.f, 0.f, 0.f, 0.f};
#pragma unroll
            for (int dc = 0; dc < 2; ++dc) {
                const bf16x8 kb = *reinterpret_cast<const bf16x8*>(
                    &Khs[(jt * 16 + r) * 64 + ((dc * 4 + g) ^ (r & 7)) * 8]);
                sac = __builtin_amdgcn_mfma_f32_16x16x32_bf16(qf[dc], kb, sac, 0, 0, 0);
            }
            const int jj = j0 + jt * 16 + r;
            const float kn_v = kn_a[h * NSEQ + jj];
            const float ck_v = ck_a[h * NSEQ + jj];
#pragma unroll
            for (int rg = 0; rg < 4; ++rg) {
                const float dsq = fmaf(-2.f, sac[rg], qn_r[rg] + kn_v);
                const float ca  = fmaxf(fmaf(dsq, c2q[rg] * ck_v, 1.f), 1.0f);
                const float s2  = fmaf(ca, ca, -1.f);
                const float wj  = ca - __builtin_amdgcn_sqrtf(s2);
                l_acc[rg] += wj;
                const int qrow = g * 4 + rg;
                Pw[qrow * 64 +
                   ((2 * jt + (r >> 3)) ^ (qrow & 7)) * 8 + (r & 7)] = f2bf(wj);
            }
        }

#pragma unroll
        for (int kc = 0; kc < 2; ++kc) {
            const bf16x8 pa = *reinterpret_cast<const bf16x8*>(
                &Pw[r * 64 + ((kc * 4 + g) ^ (r & 7)) * 8]);
#pragma unroll
            for (int nt = 0; nt < 4; ++nt) {
                const bf16x8 vb = *reinterpret_cast<const bf16x8*>(
                    &Vts[(nt * 16 + r) * 64 + ((kc * 4 + g) ^ (r & 7)) * 8]);
                oacc[nt] = __builtin_amdgcn_mfma_f32_16x16x32_bf16(pa, vb, oacc[nt], 0, 0, 0);
            }
        }
    }

#pragma unroll
    for (int rg = 0; rg < 4; ++rg) {
        l_acc[rg] += __shfl_xor(l_acc[rg], 1, 64);
        l_acc[rg] += __shfl_xor(l_acc[rg], 2, 64);
        l_acc[rg] += __shfl_xor(l_acc[rg], 4, 64);
        l_acc[rg] += __shfl_xor(l_acc[rg], 8, 64);
    }

    float* Op = Opart + (size_t)jh * NSEQ * DMODEL;
#pragma unroll
    for (int nt = 0; nt < 4; ++nt)
#pragma unroll
        for (int rg = 0; rg < 4; ++rg)
            Op[(size_t)(qb + g * 4 + rg) * DMODEL + h * HD + nt * 16 + r] =
                oacc[nt][rg];
    if (r == 0) {
#pragma unroll
        for (int rg = 0; rg < 4; ++rg)
            lpart[(jh * NHEADS + h) * NSEQ + qb + g * 4 + rg] = l_acc[rg];
    }
}

// ---------------------------------------------------------------------------
// Merge j-split partials: Ob = bf16(sum_p O_p / sum_p l_p).
// ---------------------------------------------------------------------------
__global__ __launch_bounds__(256) void merge_kernel(
    const float* __restrict__ Opart, const float* __restrict__ lpart,
    unsigned short* __restrict__ Ob, int njh)
{
    const size_t i8 = ((size_t)blockIdx.x * 256 + threadIdx.x) * 8;
    if (i8 >= (size_t)NSEQ * DMODEL) return;
    const int n  = (int)(i8 >> 10);
    const int dm = (int)(i8 & 1023);
    const int h  = dm >> 6;
    float lsum = 0.f;
    for (int p = 0; p < njh; ++p)
        lsum += lpart[(p * NHEADS + h) * NSEQ + n];
    const float li = 1.0f / lsum;
    float s[8] = {0.f, 0.f, 0.f, 0.f, 0.f, 0.f, 0.f, 0.f};
    for (int p = 0; p < njh; ++p) {
        const float* Opp = Opart + (size_t)p * NSEQ * DMODEL + i8;
#pragma unroll
        for (int c = 0; c < 2; ++c) {
            const float4 a = *reinterpret_cast<const float4*>(Opp + c * 4);
            s[c * 4 + 0] += a.x; s[c * 4 + 1] += a.y;
            s[c * 4 + 2] += a.z; s[c * 4 + 3] += a.w;
        }
    }
    ushort8_t o;
#pragma unroll
    for (int c = 0; c < 8; ++c) o[c] = f2bf(s[c] * li);
    *reinterpret_cast<ushort8_t*>(Ob + i8) = o;
}

// ---------------------------------------------------------------------------
extern "C" void kernel_launch(void* const* d_in, const int* in_sizes, int n_in,
                              void* d_out, int out_size, void* d_ws, size_t ws_size,
                              hipStream_t stream)
{
    const float* x  = (const float*)d_in[0];
    const float* Wq = (const float*)d_in[1];
    const float* Wk = (const float*)d_in[2];
    const float* Wv = (const float*)d_in[3];
    const float* Wo = (const float*)d_in[4];
    float* out = (float*)d_out;

    char* ws = (char*)d_ws;
    const size_t MB = 1048576;
    unsigned short* xb   = (unsigned short*)(ws);             // 4MB (-> Ob)
    unsigned short* Wb   = (unsigned short*)(ws + 4  * MB);   // 6MB
    unsigned short* Wob  = (unsigned short*)(ws + 10 * MB);   // 2MB
    unsigned short* Qbuf = (unsigned short*)(ws + 12 * MB);   // 4MB
    unsigned short* Kbuf = (unsigned short*)(ws + 16 * MB);   // 4MB
    unsigned short* Vb   = (unsigned short*)(ws + 20 * MB);   // 4MB
    unsigned short* Vt   = (unsigned short*)(ws + 24 * MB);   // 4MB
    float*          qn   = (float*)(ws + 28 * MB);            // 128KB
    float*          cq2  = qn  + NHEADS * NSEQ;
    float*          kn   = cq2 + NHEADS * NSEQ;
    float*          ck   = kn  + NHEADS * NSEQ;
    float*          Opart= (float*)(ws + 29 * MB);            // njh*8MB
    unsigned short* Ob   = xb;   // xb dead after QKV GEMM

    // occupancy-driven j-split; fall back if workspace is small
    const int njh = (ws_size >= 63 * MB) ? 4 : 2;
    float* lpart = (float*)(ws + (29 + (size_t)njh * 8) * MB); // 256KB-512KB
    const int jspan = NSEQ / njh;

    const dim3 blk(256);

    // 1. fp32 -> bf16 conversions
    convert_inputs<<<3072, blk, 0, stream>>>(x, Wq, Wk, Wv, Wo, xb, Wb, Wob);

    // 2. fused QKV projection (bf16 in/out) + norms in epilogue  [768 blocks]
    gemm_bt_bf16<1><<<dim3(NSEQ / 128, 3072 / 64), blk, 0, stream>>>(
        xb, Wb, nullptr, Qbuf, qn, cq2, Kbuf, kn, ck, Vb);

    // 3. V transpose to [h*64+d][n]
    vt_kernel_bf16<<<dim3(NSEQ / 64, NHEADS), blk, 0, stream>>>(Vb, Vt);

    // 4. attention partials (j-split x njh)  [up to 2048 blocks]
    hyp_attn_v3<<<dim3(NSEQ / 64, NHEADS, njh), blk, 0, stream>>>(
        Qbuf, Kbuf, Vt, qn, cq2, kn, ck, Opart, lpart, jspan);

    // 5. merge partials -> Ob (bf16)
    merge_kernel<<<(NSEQ * DMODEL / 8 + 255) / 256, blk, 0, stream>>>(
        Opart, lpart, Ob, njh);

    // 6. output projection  [256 blocks]
    gemm_bt_bf16<0><<<dim3(NSEQ / 128, DMODEL / 64), blk, 0, stream>>>(
        Ob, Wob, out, nullptr, nullptr, nullptr,
        nullptr, nullptr, nullptr, nullptr);
}

// Round 12
// 95.082 us; speedup vs baseline: 1.7591x; 1.1120x over previous
//
#include <hip/hip_runtime.h>
#include <math.h>

#define NSEQ   2048
#define DMODEL 1024
#define NHEADS 16
#define HD     64
#define NJH    2
#define JSPAN  (NSEQ / NJH)

typedef short bf16x8 __attribute__((ext_vector_type(8)));
typedef float f32x4  __attribute__((ext_vector_type(4)));
typedef unsigned short ushort8_t __attribute__((ext_vector_type(8)));

// RTNE float -> bf16 bits
__device__ __forceinline__ unsigned short f2bf(float x) {
    unsigned int u = __builtin_bit_cast(unsigned int, x);
    unsigned int r = (u + 0x7FFFu + ((u >> 16) & 1u)) >> 16;
    return (unsigned short)r;
}

// ---------------------------------------------------------------------------
// Convert inputs to bf16: x(2M)->xb, Wq/Wk/Wv(3x1M)->Wb[3072][1024], Wo->Wob.
// ---------------------------------------------------------------------------
__global__ __launch_bounds__(256) void convert_inputs(
    const float* __restrict__ x,  const float* __restrict__ Wq,
    const float* __restrict__ Wk, const float* __restrict__ Wv,
    const float* __restrict__ Wo,
    unsigned short* __restrict__ xb, unsigned short* __restrict__ Wb,
    unsigned short* __restrict__ Wob)
{
    const size_t i8 = ((size_t)blockIdx.x * 256 + threadIdx.x) * 8;
    const float* src;
    unsigned short* dst;
    if (i8 < (2ull << 20)) {
        src = x + i8;  dst = xb + i8;
    } else if (i8 < (5ull << 20)) {
        const size_t o = i8 - (2ull << 20);
        const size_t s = o >> 20;
        src = (s == 0 ? Wq : (s == 1 ? Wk : Wv)) + (o & ((1u << 20) - 1));
        dst = Wb + o;
    } else {
        const size_t o = i8 - (5ull << 20);
        src = Wo + o;  dst = Wob + o;
    }
    const float4 v0 = *reinterpret_cast<const float4*>(src);
    const float4 v1 = *reinterpret_cast<const float4*>(src + 4);
    ushort8_t r;
    r[0] = f2bf(v0.x); r[1] = f2bf(v0.y); r[2] = f2bf(v0.z); r[3] = f2bf(v0.w);
    r[4] = f2bf(v1.x); r[5] = f2bf(v1.y); r[6] = f2bf(v1.z); r[7] = f2bf(v1.w);
    *reinterpret_cast<ushort8_t*>(dst) = r;
}

// ---------------------------------------------------------------------------
// bf16 MFMA GEMM (B-transposed), BM=128 x BN=64, BK=64; 4 waves stacked in M.
// T14 async-STAGE: tile k0+64's global loads issue right after tile k0's
// ds_writes, hiding load latency under the MFMA phase.
// LDS: linear 64-u16 rows + XOR colseg swizzle (verified family, R7).
// ---------------------------------------------------------------------------
template <int QKV>
__global__ __launch_bounds__(256) void gemm_bt_bf16(
    const unsigned short* __restrict__ A, const unsigned short* __restrict__ B,
    float* __restrict__ C0,
    unsigned short* __restrict__ QbO, float* __restrict__ qnO,
    float* __restrict__ cq2O,
    unsigned short* __restrict__ KbO, float* __restrict__ knO,
    float* __restrict__ ckO,
    unsigned short* __restrict__ VbO)
{
    __shared__ unsigned short Ahs[128 * 64];
    __shared__ unsigned short Bhs[64 * 64];

    const int bm   = blockIdx.x * 128;
    const int bn   = blockIdx.y * 64;
    const int t    = threadIdx.x;
    const int wid  = t >> 6;
    const int lane = t & 63;
    const int g    = lane >> 4;
    const int r    = lane & 15;
    const int wm   = wid * 32;           // wave tile 32(M) x 64(N)

    const int sel = QKV ? (bn >> 10) : 0;
    const int bnl = QKV ? (bn & 1023) : bn;

    f32x4 acc[2][4];
#pragma unroll
    for (int i = 0; i < 2; ++i)
#pragma unroll
        for (int j = 0; j < 4; ++j) acc[i][j] = (f32x4){0.f, 0.f, 0.f, 0.f};

    const int srowA = t >> 1;        // 0..127
    const int shalA = t & 1;         // k-half
    const int srowB = t >> 2;        // 0..63
    const int squadB = t & 3;

    const unsigned short* Ag = &A[(size_t)(bm + srowA) * DMODEL + shalA * 32];
    const unsigned short* Bg = &B[(size_t)(bn + srowB) * DMODEL + squadB * 16];

    ushort8_t av[4], bv[2];
#pragma unroll
    for (int c = 0; c < 4; ++c)
        av[c] = *reinterpret_cast<const ushort8_t*>(Ag + c * 8);
#pragma unroll
    for (int c = 0; c < 2; ++c)
        bv[c] = *reinterpret_cast<const ushort8_t*>(Bg + c * 8);

    for (int k0 = 0; k0 < DMODEL; k0 += 64) {
        __syncthreads();
#pragma unroll
        for (int c = 0; c < 4; ++c) {
            const int sw = ((shalA * 4 + c) ^ (srowA & 7)) * 8;
            *reinterpret_cast<ushort8_t*>(&Ahs[srowA * 64 + sw]) = av[c];
        }
#pragma unroll
        for (int c = 0; c < 2; ++c) {
            const int sw = ((squadB * 2 + c) ^ (srowB & 7)) * 8;
            *reinterpret_cast<ushort8_t*>(&Bhs[srowB * 64 + sw]) = bv[c];
        }
        if (k0 + 64 < DMODEL) {   // issue next-tile loads (overlap with MFMAs)
#pragma unroll
            for (int c = 0; c < 4; ++c)
                av[c] = *reinterpret_cast<const ushort8_t*>(
                    Ag + k0 + 64 + c * 8);
#pragma unroll
            for (int c = 0; c < 2; ++c)
                bv[c] = *reinterpret_cast<const ushort8_t*>(
                    Bg + k0 + 64 + c * 8);
        }
        __syncthreads();

#pragma unroll
        for (int dc = 0; dc < 2; ++dc) {
            bf16x8 af[2], bfr[4];
#pragma unroll
            for (int mt = 0; mt < 2; ++mt)
                af[mt] = *reinterpret_cast<const bf16x8*>(
                    &Ahs[(wm + mt * 16 + r) * 64 + ((dc * 4 + g) ^ (r & 7)) * 8]);
#pragma unroll
            for (int nt = 0; nt < 4; ++nt)
                bfr[nt] = *reinterpret_cast<const bf16x8*>(
                    &Bhs[(nt * 16 + r) * 64 + ((dc * 4 + g) ^ (r & 7)) * 8]);
#pragma unroll
            for (int mt = 0; mt < 2; ++mt)
#pragma unroll
                for (int nt = 0; nt < 4; ++nt)
                    acc[mt][nt] = __builtin_amdgcn_mfma_f32_16x16x32_bf16(
                        af[mt], bfr[nt], acc[mt][nt], 0, 0, 0);
        }
    }

    if (QKV) {
        if (sel < 2) {
            unsigned short* Hb = sel ? KbO : QbO;
            float* narr = sel ? knO : qnO;
            float* carr = sel ? ckO : cq2O;
            const int hh = bnl >> 6;   // one head per block (64 cols)
#pragma unroll
            for (int mt = 0; mt < 2; ++mt) {
#pragma unroll
                for (int rg = 0; rg < 4; ++rg) {
                    float ss = 0.f;
#pragma unroll
                    for (int nt = 0; nt < 4; ++nt) {
                        const float v = acc[mt][nt][rg];
                        ss = fmaf(v, v, ss);
                        Hb[(size_t)(bm + wm + mt * 16 + g * 4 + rg) * 1024 +
                           bnl + nt * 16 + r] = f2bf(v);
                    }
                    ss += __shfl_xor(ss, 1, 64);
                    ss += __shfl_xor(ss, 2, 64);
                    ss += __shfl_xor(ss, 4, 64);
                    ss += __shfl_xor(ss, 8, 64);
                    if (r == 0) {
                        const int row = bm + wm + mt * 16 + g * 4 + rg;
                        narr[hh * NSEQ + row] = ss;
                        carr[hh * NSEQ + row] = (sel ? 1.0f : 2.0f) / (1.0f - ss);
                    }
                }
            }
        } else {
#pragma unroll
            for (int mt = 0; mt < 2; ++mt)
#pragma unroll
                for (int nt = 0; nt < 4; ++nt)
#pragma unroll
                    for (int rg = 0; rg < 4; ++rg)
                        VbO[(size_t)(bm + wm + mt * 16 + g * 4 + rg) * 1024 +
                            bnl + nt * 16 + r] = f2bf(acc[mt][nt][rg]);
        }
    } else {
#pragma unroll
        for (int mt = 0; mt < 2; ++mt)
#pragma unroll
            for (int nt = 0; nt < 4; ++nt)
#pragma unroll
                for (int rg = 0; rg < 4; ++rg)
                    C0[(size_t)(bm + wm + mt * 16 + g * 4 + rg) * 1024 +
                       bnl + nt * 16 + r] = acc[mt][nt][rg];
    }
}

// ---------------------------------------------------------------------------
// Per-head V transpose (bf16->bf16): Vt[(h*64+d)*2048 + n] = Vb[n*1024+h*64+d]
// ---------------------------------------------------------------------------
__global__ __launch_bounds__(256) void vt_kernel_bf16(
    const unsigned short* __restrict__ Vb, unsigned short* __restrict__ Vt)
{
    __shared__ unsigned short Vs[64 * 72];
    const int h   = blockIdx.y;
    const int n0  = blockIdx.x * 64;
    const int t   = threadIdx.x;
    const int row = t >> 2;
    const int seg = (t & 3) * 16;

    const unsigned short* src = Vb + (size_t)(n0 + row) * 1024 + h * HD + seg;
    *reinterpret_cast<ushort8_t*>(&Vs[row * 72 + seg]) =
        *reinterpret_cast<const ushort8_t*>(src);
    *reinterpret_cast<ushort8_t*>(&Vs[row * 72 + seg + 8]) =
        *reinterpret_cast<const ushort8_t*>(src + 8);
    __syncthreads();

    ushort8_t a, b;
#pragma unroll
    for (int c = 0; c < 8; ++c) a[c] = Vs[(seg + c) * 72 + row];
#pragma unroll
    for (int c = 0; c < 8; ++c) b[c] = Vs[(seg + 8 + c) * 72 + row];
    unsigned short* dst = Vt + (size_t)(h * HD + row) * NSEQ + n0 + seg;
    *reinterpret_cast<ushort8_t*>(dst)     = a;
    *reinterpret_cast<ushort8_t*>(dst + 8) = b;
}

// ---------------------------------------------------------------------------
// MFMA hyperbolic attention v5 = v3 core (R7-verified layouts) + T14:
//  - kn/ck for the whole j-span staged into LDS once (removes per-tile
//    global gathers from the distance critical path);
//  - next tile's K/V global loads issued right after current ds_writes,
//    hiding ~200-500cy load latency under the ~1000cy compute phase.
// Grid (NSEQ/64, NHEADS, NJH). 4 waves; wave w: q rows [n0+16w,+16).
// ---------------------------------------------------------------------------
__global__ __launch_bounds__(256) void hyp_attn_v5(
    const unsigned short* __restrict__ Qb, const unsigned short* __restrict__ Kb,
    const unsigned short* __restrict__ Vt,
    const float* __restrict__ qn_a, const float* __restrict__ cq2_a,
    const float* __restrict__ kn_a, const float* __restrict__ ck_a,
    float* __restrict__ Opart, float* __restrict__ lpart)
{
    __shared__ unsigned short Khs[64 * 64];   // [j][k-seg swz]
    __shared__ unsigned short Vts[64 * 64];   // [d][j-seg swz]
    __shared__ unsigned short Ps[4][16 * 64]; // per-wave [q][j-seg swz]
    __shared__ float kns[JSPAN];
    __shared__ float cks[JSPAN];

    const int h    = blockIdx.y;
    const int n0   = blockIdx.x * 64;
    const int jh   = blockIdx.z;
    const int t    = threadIdx.x;
    const int wid  = t >> 6;
    const int lane = t & 63;
    const int g    = lane >> 4;
    const int r    = lane & 15;
    const int qb   = n0 + wid * 16;

    // ---- prologue: Q frags, per-q constants, kn/ck span -> LDS ----
    bf16x8 qf[2];
#pragma unroll
    for (int dc = 0; dc < 2; ++dc)
        qf[dc] = *reinterpret_cast<const bf16x8*>(
            Qb + (size_t)(qb + r) * DMODEL + h * HD + dc * 32 + g * 8);

    float qn_r[4], c2q[4];
#pragma unroll
    for (int rg = 0; rg < 4; ++rg) {
        qn_r[rg] = qn_a[h * NSEQ + qb + g * 4 + rg];
        c2q[rg]  = cq2_a[h * NSEQ + qb + g * 4 + rg];
    }
#pragma unroll
    for (int i = 0; i < JSPAN / 256; ++i) {
        kns[i * 256 + t] = kn_a[h * NSEQ + jh * JSPAN + i * 256 + t];
        cks[i * 256 + t] = ck_a[h * NSEQ + jh * JSPAN + i * 256 + t];
    }

    f32x4 oacc[4];
#pragma unroll
    for (int nt = 0; nt < 4; ++nt) oacc[nt] = (f32x4){0.f, 0.f, 0.f, 0.f};
    float l_acc[4] = {0.f, 0.f, 0.f, 0.f};

    const int srow = t >> 2;
    const int c0   = (t & 3) * 2;
    const int sw0  = (c0 ^ (srow & 7)) * 8;
    const int sw1  = ((c0 + 1) ^ (srow & 7)) * 8;
    const int sg   = (t & 3) * 16;
    unsigned short* Pw = &Ps[wid][0];

    const unsigned short* Kg = Kb + (size_t)(jh * JSPAN + srow) * DMODEL + h * HD + sg;
    const unsigned short* Vg = Vt + (size_t)(h * HD + srow) * NSEQ + jh * JSPAN + sg;

    // prefetch tile 0 into regs
    ushort8_t kr0 = *reinterpret_cast<const ushort8_t*>(Kg);
    ushort8_t kr1 = *reinterpret_cast<const ushort8_t*>(Kg + 8);
    ushort8_t vr0 = *reinterpret_cast<const ushort8_t*>(Vg);
    ushort8_t vr1 = *reinterpret_cast<const ushort8_t*>(Vg + 8);

    const int ntb = JSPAN / 64;
    for (int tb = 0; tb < ntb; ++tb) {
        __syncthreads();   // prev tile consumed; (tb=0) kns/cks visible
        // ---- write current tile regs -> LDS (swizzled) ----
        *reinterpret_cast<ushort8_t*>(&Khs[srow * 64 + sw0]) = kr0;
        *reinterpret_cast<ushort8_t*>(&Khs[srow * 64 + sw1]) = kr1;
        *reinterpret_cast<ushort8_t*>(&Vts[srow * 64 + sw0]) = vr0;
        *reinterpret_cast<ushort8_t*>(&Vts[srow * 64 + sw1]) = vr1;
        // ---- issue next tile loads (latency hides under compute) ----
        if (tb + 1 < ntb) {
            const unsigned short* kn_ = Kg + (size_t)(tb + 1) * 64 * DMODEL;
            const unsigned short* vn_ = Vg + (tb + 1) * 64;
            kr0 = *reinterpret_cast<const ushort8_t*>(kn_);
            kr1 = *reinterpret_cast<const ushort8_t*>(kn_ + 8);
            vr0 = *reinterpret_cast<const ushort8_t*>(vn_);
            vr1 = *reinterpret_cast<const ushort8_t*>(vn_ + 8);
        }
        __syncthreads();

        // ---- S tiles + distance -> w -> P (swizzled wave-private LDS) ----
#pragma unroll
        for (int jt = 0; jt < 4; ++jt) {
            f32x4 sac = (f32x4){0.f, 0.f, 0.f, 0.f};
#pragma unroll
            for (int dc = 0; dc < 2; ++dc) {
                const bf16x8 kb = *reinterpret_cast<const bf16x8*>(
                    &Khs[(jt * 16 + r) * 64 + ((dc * 4 + g) ^ (r & 7)) * 8]);
                sac = __builtin_amdgcn_mfma_f32_16x16x32_bf16(qf[dc], kb, sac, 0, 0, 0);
            }
            const int jl = tb * 64 + jt * 16 + r;
            const float kn_v = kns[jl];
            const float ck_v = cks[jl];
#pragma unroll
            for (int rg = 0; rg < 4; ++rg) {
                const float dsq = fmaf(-2.f, sac[rg], qn_r[rg] + kn_v);
                const float ca  = fmaxf(fmaf(dsq, c2q[rg] * ck_v, 1.f), 1.0f);
                const float s2  = fmaf(ca, ca, -1.f);
                const float wj  = ca - __builtin_amdgcn_sqrtf(s2);
                l_acc[rg] += wj;
                const int qrow = g * 4 + rg;
                Pw[qrow * 64 +
                   ((2 * jt + (r >> 3)) ^ (qrow & 7)) * 8 + (r & 7)] = f2bf(wj);
            }
        }
        // Pw is wave-private: within-wave ds ordering suffices

        // ---- PV: O[q][d] += P . V ----
#pragma unroll
        for (int kc = 0; kc < 2; ++kc) {
            const bf16x8 pa = *reinterpret_cast<const bf16x8*>(
                &Pw[r * 64 + ((kc * 4 + g) ^ (r & 7)) * 8]);
#pragma unroll
            for (int nt = 0; nt < 4; ++nt) {
                const bf16x8 vb = *reinterpret_cast<const bf16x8*>(
                    &Vts[(nt * 16 + r) * 64 + ((kc * 4 + g) ^ (r & 7)) * 8]);
                oacc[nt] = __builtin_amdgcn_mfma_f32_16x16x32_bf16(pa, vb, oacc[nt], 0, 0, 0);
            }
        }
    }

    // ---- l reduce over the 16 r-lanes ----
#pragma unroll
    for (int rg = 0; rg < 4; ++rg) {
        l_acc[rg] += __shfl_xor(l_acc[rg], 1, 64);
        l_acc[rg] += __shfl_xor(l_acc[rg], 2, 64);
        l_acc[rg] += __shfl_xor(l_acc[rg], 4, 64);
        l_acc[rg] += __shfl_xor(l_acc[rg], 8, 64);
    }

    // ---- write partials ----
    float* Op = Opart + (size_t)jh * NSEQ * DMODEL;
#pragma unroll
    for (int nt = 0; nt < 4; ++nt)
#pragma unroll
        for (int rg = 0; rg < 4; ++rg)
            Op[(size_t)(qb + g * 4 + rg) * DMODEL + h * HD + nt * 16 + r] =
                oacc[nt][rg];
    if (r == 0) {
#pragma unroll
        for (int rg = 0; rg < 4; ++rg)
            lpart[(jh * NHEADS + h) * NSEQ + qb + g * 4 + rg] = l_acc[rg];
    }
}

// ---------------------------------------------------------------------------
// Merge j-split partials: Ob = bf16((O0+O1) / (l0+l1)).
// ---------------------------------------------------------------------------
__global__ __launch_bounds__(256) void merge_kernel(
    const float* __restrict__ Opart, const float* __restrict__ lpart,
    unsigned short* __restrict__ Ob)
{
    const size_t i8 = ((size_t)blockIdx.x * 256 + threadIdx.x) * 8;
    if (i8 >= (size_t)NSEQ * DMODEL) return;
    const int n  = (int)(i8 >> 10);
    const int dm = (int)(i8 & 1023);
    const int h  = dm >> 6;
    const float li = 1.0f / (lpart[h * NSEQ + n] +
                             lpart[(NHEADS + h) * NSEQ + n]);
    const float* O0 = Opart + i8;
    const float* O1 = Opart + (size_t)NSEQ * DMODEL + i8;
    ushort8_t o;
#pragma unroll
    for (int c = 0; c < 2; ++c) {
        const float4 a = *reinterpret_cast<const float4*>(O0 + c * 4);
        const float4 b = *reinterpret_cast<const float4*>(O1 + c * 4);
        o[c * 4 + 0] = f2bf((a.x + b.x) * li);
        o[c * 4 + 1] = f2bf((a.y + b.y) * li);
        o[c * 4 + 2] = f2bf((a.z + b.z) * li);
        o[c * 4 + 3] = f2bf((a.w + b.w) * li);
    }
    *reinterpret_cast<ushort8_t*>(Ob + i8) = o;
}

// ---------------------------------------------------------------------------
extern "C" void kernel_launch(void* const* d_in, const int* in_sizes, int n_in,
                              void* d_out, int out_size, void* d_ws, size_t ws_size,
                              hipStream_t stream)
{
    const float* x  = (const float*)d_in[0];
    const float* Wq = (const float*)d_in[1];
    const float* Wk = (const float*)d_in[2];
    const float* Wv = (const float*)d_in[3];
    const float* Wo = (const float*)d_in[4];
    float* out = (float*)d_out;

    char* ws = (char*)d_ws;
    const size_t MB = 1048576;
    unsigned short* xb   = (unsigned short*)(ws);             // 4MB (-> Ob)
    unsigned short* Wb   = (unsigned short*)(ws + 4  * MB);   // 6MB
    unsigned short* Wob  = (unsigned short*)(ws + 10 * MB);   // 2MB
    unsigned short* Qbuf = (unsigned short*)(ws + 12 * MB);   // 4MB
    unsigned short* Kbuf = (unsigned short*)(ws + 16 * MB);   // 4MB
    unsigned short* Vb   = (unsigned short*)(ws + 20 * MB);   // 4MB
    unsigned short* Vt   = (unsigned short*)(ws + 24 * MB);   // 4MB
    float*          qn   = (float*)(ws + 28 * MB);            // 128KB
    float*          cq2  = qn  + NHEADS * NSEQ;
    float*          kn   = cq2 + NHEADS * NSEQ;
    float*          ck   = kn  + NHEADS * NSEQ;
    float*          Opart= (float*)(ws + 29 * MB);            // 16MB
    float*          lpart= (float*)(ws + 45 * MB);            // 256KB
    unsigned short* Ob   = xb;   // xb dead after QKV GEMM

    const dim3 blk(256);

    // 1. fp32 -> bf16 conversions
    convert_inputs<<<3072, blk, 0, stream>>>(x, Wq, Wk, Wv, Wo, xb, Wb, Wob);

    // 2. fused QKV projection + norms in epilogue  [768 blocks]
    gemm_bt_bf16<1><<<dim3(NSEQ / 128, 3072 / 64), blk, 0, stream>>>(
        xb, Wb, nullptr, Qbuf, qn, cq2, Kbuf, kn, ck, Vb);

    // 3. V transpose to [h*64+d][n]
    vt_kernel_bf16<<<dim3(NSEQ / 64, NHEADS), blk, 0, stream>>>(Vb, Vt);

    // 4. attention partials (j-split x2, T14 pipeline)  [1024 blocks]
    hyp_attn_v5<<<dim3(NSEQ / 64, NHEADS, NJH), blk, 0, stream>>>(
        Qbuf, Kbuf, Vt, qn, cq2, kn, ck, Opart, lpart);

    // 5. merge partials -> Ob (bf16)
    merge_kernel<<<(NSEQ * DMODEL / 8 + 255) / 256, blk, 0, stream>>>(
        Opart, lpart, Ob);

    // 6. output projection  [256 blocks]
    gemm_bt_bf16<0><<<dim3(NSEQ / 128, DMODEL / 64), blk, 0, stream>>>(
        Ob, Wob, out, nullptr, nullptr, nullptr,
        nullptr, nullptr, nullptr, nullptr);
}